// Round 4
// baseline (1401.126 us; speedup 1.0000x reference)
//
#include <hip/hip_runtime.h>
#include <math.h>

#define CIN   16
#define DDEP  8      // conv depth (routing "D")
#define HIN   96
#define WIN   96
#define HOUT  94
#define WOUT  94
#define HW    (HOUT*WOUT)        // 8836
#define CH    256                 // out channels = c*8+d
#define DCAP  8
#define KTOT  (CIN*9)             // 144
#define KTILES 5                  // K padded to 160
#define APAD  168                 // A row stride (bf16 elems)
#define EPSQ  1e-8f

#define B_ELEMS ((size_t)8*DDEP*DCAP*HW)          // 4,524,032 floats
#define WFRAG_ELEMS ((size_t)KTILES*16*64*8)      // 40,960 per half
#define VSITES (DCAP*HW)                          // 70,688 sites per batch
#define NBLK2  277                                // ceil(70688/256)
#define XN ((size_t)8*CIN*DDEP*HIN*WIN)           // 9,437,184 x elems
#define G_BYTES ((size_t)8*VSITES*36*4)           // 81,432,576 B

typedef __attribute__((ext_vector_type(8))) short bf16x8;
typedef __attribute__((ext_vector_type(4))) float f32x4;

// explicit RNE float->bf16 bit conversion
__device__ __forceinline__ ushort f2bf(float f) {
    unsigned u = __float_as_uint(f);
    return (ushort)((u + 0x7FFFu + ((u >> 16) & 1u)) >> 16);
}
__device__ __forceinline__ float bf2f(ushort h) {
    return __uint_as_float(((unsigned)h) << 16);
}

// ---------------------------------------------------------------------------
// W -> MFMA B-fragment order, hi/lo split. frag[kt][nt][lane][j] = W[k][n],
// k = kt*32 + (lane>>4)*8 + j (0 for k>=144), n = nt*16 + (lane&15).
// ---------------------------------------------------------------------------
__global__ __launch_bounds__(64) void build_wfrag(
    const float* __restrict__ w, ushort* __restrict__ w_hi, ushort* __restrict__ w_lo)
{
    const int lane = threadIdx.x;
    const int nt = blockIdx.x, kt = blockIdx.y;
    const int n  = nt*16 + (lane & 15);
    const int kb = kt*32 + (lane >> 4)*8;
    size_t off = (((size_t)kt*16 + nt)*64 + lane)*8;
    for (int j = 0; j < 8; ++j) {
        int k = kb + j;
        float v = (k < KTOT) ? w[(size_t)n*KTOT + k] : 0.f;
        ushort hi = f2bf(v);
        float  r  = v - bf2f(hi);
        ushort lo = f2bf(r);
        w_hi[off + j] = hi; w_lo[off + j] = lo;
    }
}

// ---------------------------------------------------------------------------
// r13: one-shot x -> bf16 side-cache (18.9 MB). Both conv passes stage ushort
// patches from this (identical bits to in-pass f2bf -> bitwise-same A tiles).
// ---------------------------------------------------------------------------
__global__ __launch_bounds__(256) void xconvert(
    const float* __restrict__ x, ushort* __restrict__ xb)
{
    size_t i = (size_t)blockIdx.x*256 + threadIdx.x;
    if (i*4 >= XN) return;
    float4 v = ((const float4*)x)[i];
    ushort4 o;
    o.x = f2bf(v.x); o.y = f2bf(v.y); o.z = f2bf(v.z); o.w = f2bf(v.w);
    ((ushort4*)xb)[i] = o;
}

// ---------------------------------------------------------------------------
// Z reduce from contention-free per-block partials (r10 lesson: NEVER funnel
// per-block Z through same-address device atomics — serialized ~+120us/pass).
// ---------------------------------------------------------------------------
__global__ __launch_bounds__(256) void zreduce(
    const float* __restrict__ Zp, float* __restrict__ Z, int dst, int count)
{
    const int bd = blockIdx.x;
    const float* p = Zp + (size_t)bd * count;
    float s = 0.f;
    for (int i = threadIdx.x; i < count; i += 256) s += p[i];
    #pragma unroll
    for (int off = 1; off < 64; off <<= 1) s += __shfl_xor(s, off);
    __shared__ float ps[4];
    if ((threadIdx.x & 63) == 0) ps[threadIdx.x >> 6] = s;
    __syncthreads();
    if (threadIdx.x == 0) Z[dst + bd] = ps[0] + ps[1] + ps[2] + ps[3];
}

// ---------------------------------------------------------------------------
// r13 pass A: implicit-GEMM MFMA conv -> per-site 8x8 Gram matrix ONLY.
// Block: (wx,h0,bb) -> 8 D x 1 h-row x 8 w; M=64, N=256.
// acc[mt][nt][r]: m = mt*16 + quad*4 + r -> D = mt*2 + (quad>>1),
//                 wi = (quad&1)*4 + r;  ch = wv*64 + nt*16 + m16.
// G_DD'(d,wi) = sum_c u_cD*u_cD' (36 sym entries). Accumulation order
// (nt, xor-8, 4-wave LDS) is bit-identical to the r12-validated Gm.
// r12 lesson (rule #20): NO runtime-indexed register arrays — the u8 fill
// uses cndmask selects with static indices (r12's u8[..+Dq] went to scratch,
// ~256 scratch ops/thread = the +85us regression).
// ---------------------------------------------------------------------------
__global__ __launch_bounds__(256, 4) void conv_g(
    const ushort* __restrict__ xb,
    const ushort* __restrict__ w_hi, const ushort* __restrict__ w_lo,
    float* __restrict__ Gm)
{
    const int t  = threadIdx.x;
    const int wx = blockIdx.x, h0 = blockIdx.y, bb = blockIdx.z;
    const int w0 = wx*8;

    __shared__ __align__(16) ushort a_hi[64][APAD];  // 21504 B (all phases)
    __shared__ union {                               // 18432 B, lifetime-disjoint
        ushort patchb[CIN][DDEP][3][10];             //   phases 0-1 (7680 B)
        float  gst[2][4][16][36];                    //   Gram staging (post-MFMA)
    } ov;

    // ---- phase 0: stage bf16 x patch (uint pair loads, clamped tail) ----
    for (int i = t; i < CIN*DDEP*3*5; i += 256) {
        int ci = i / 120, rem = i - ci*120;
        int D  = rem / 15, r2 = rem - D*15;
        int kh = r2 / 5, uc = r2 - kh*5;
        int xc = w0 + uc*2;
        const ushort* row = xb + (((size_t)(bb*CIN + ci)*DDEP + D)*HIN + (h0+kh))*WIN;
        unsigned v;
        if (xc + 1 < WIN) v = *(const unsigned*)&row[xc];
        else { unsigned e = row[95]; v = e | (e << 16); }  // clamp: garbage cols feed only invalid sites
        *(unsigned*)&ov.patchb[ci][D][kh][uc*2] = v;
    }
    __syncthreads();

    // ---- phase 1: im2col (pure ushort packing; no f2bf) ----
    {
        const int site = t >> 2, kg = t & 3;     // site = D*8 + wi
        const int D = site >> 3, wi = site & 7;
        #pragma unroll
        for (int u2 = 0; u2 < 18; ++u2) {
            int k0 = kg*36 + u2*2;
            int ci0 = k0/9, r0 = k0 - ci0*9, kh0 = r0/3, kw0 = r0 - kh0*3;
            int k1 = k0 + 1;
            int ci1 = k1/9, r1 = k1 - ci1*9, kh1 = r1/3, kw1 = r1 - kh1*3;
            unsigned lo = ov.patchb[ci0][D][kh0][wi+kw0];
            unsigned hi = ov.patchb[ci1][D][kh1][wi+kw1];
            *(unsigned*)&a_hi[site][k0] = lo | (hi << 16);
        }
        if (t < 64) {
            #pragma unroll
            for (int kk = KTOT; kk < KTILES*32; kk += 2)
                *(unsigned*)&a_hi[t][kk] = 0u;
        }
    }
    __syncthreads();

    // ---- phase 2: MFMA K-loop ----
    const int wv = t >> 6, lane = t & 63;
    const int m16 = lane & 15, quad = lane >> 4;
    const int Dq = quad >> 1, wih = quad & 1;
    f32x4 acc[4][4];
    #pragma unroll
    for (int mt = 0; mt < 4; ++mt)
        #pragma unroll
        for (int nt = 0; nt < 4; ++nt)
            acc[mt][nt] = (f32x4){0.f, 0.f, 0.f, 0.f};

    #pragma unroll
    for (int kt = 0; kt < KTILES; ++kt) {
        bf16x8 ah[4];
        #pragma unroll
        for (int mt = 0; mt < 4; ++mt)
            ah[mt] = *(const bf16x8*)&a_hi[mt*16 + m16][kt*32 + quad*8];
        #pragma unroll
        for (int nt = 0; nt < 4; ++nt) {
            size_t off = (((size_t)kt*16 + (wv*4 + nt))*64 + lane)*8;
            bf16x8 bh = *(const bf16x8*)&w_hi[off];
            bf16x8 bl = *(const bf16x8*)&w_lo[off];
            #pragma unroll
            for (int mt = 0; mt < 4; ++mt) {
                acc[mt][nt] = __builtin_amdgcn_mfma_f32_16x16x32_bf16(ah[mt], bh, acc[mt][nt], 0, 0, 0);
                acc[mt][nt] = __builtin_amdgcn_mfma_f32_16x16x32_bf16(ah[mt], bl, acc[mt][nt], 0, 0, 0);
            }
        }
    }

    // ---- phase 3: Gram (2-r batches, 3 barriers; all-lane, scratch-free) ----
    const int dL = m16 & 7;
    #pragma unroll
    for (int rp = 0; rp < 2; ++rp) {
        #pragma unroll
        for (int rb = 0; rb < 2; ++rb) {
            const int r = rp*2 + rb;
            float G36[36];
            #pragma unroll
            for (int j = 0; j < 36; ++j) G36[j] = 0.f;
            #pragma unroll
            for (int nt = 0; nt < 4; ++nt) {
                float u8[8];
                #pragma unroll
                for (int mt = 0; mt < 4; ++mt) {
                    float own = acc[mt][nt][r];
                    float oth = __shfl_xor(own, 32);
                    u8[mt*2]     = (Dq == 0) ? own : oth;   // D = mt*2
                    u8[mt*2 + 1] = (Dq == 0) ? oth : own;   // D = mt*2+1
                }
                int idx = 0;
                #pragma unroll
                for (int D = 0; D < 8; ++D)
                    #pragma unroll
                    for (int Dp = D; Dp < 8; ++Dp) {
                        G36[idx] += u8[D]*u8[Dp];
                        ++idx;
                    }
            }
            #pragma unroll
            for (int j = 0; j < 36; ++j) G36[j] += __shfl_xor(G36[j], 8);
            if (Dq == 0 && m16 < 8) {
                #pragma unroll
                for (int j = 0; j < 36; ++j) ov.gst[rb][wv][dL*2 + wih][j] = G36[j];
            }
        }
        __syncthreads();
        // cross-wave sum + global write: 2 x 16 sites x 36, 144B runs/site
        for (int idx2 = t; idx2 < 2*16*36; idx2 += 256) {
            int rb = idx2 / 576, rem = idx2 - rb*576;
            int sidx = rem / 36, j = rem - sidx*36;
            int dd = sidx >> 1, wh = sidx & 1;
            int w = w0 + wh*4 + rp*2 + rb;
            if (w < WOUT) {
                float gv = ov.gst[rb][0][sidx][j] + ov.gst[rb][1][sidx][j]
                         + ov.gst[rb][2][sidx][j] + ov.gst[rb][3][sidx][j];
                size_t gsite = ((size_t)(bb*DCAP + dd)*HOUT + h0)*WOUT + w;
                Gm[gsite*36 + j] = gv;
            }
        }
        if (rp == 0) __syncthreads();
    }
}

// ---------------------------------------------------------------------------
// r13: routing iterations 1 AND 2 from the Gram matrix (both pure streaming).
// ITER 1: cm uniform (no softmax needed: b0=0), b1 = fac*(G cm), Z1 partials.
// ITER 2: cm = exp(b1)/Z1, b2 = b1 + fac*(G cm), Z2 partials.
//   t_D = (G cm)_D;  n2 = cm^T G cm;  fac = (n2/(1+n2))/rsqrt-ish.
// gram iter2 path validated on-harness in r12 (passed, absmax unchanged).
// ---------------------------------------------------------------------------
template<int ITER>
__global__ __launch_bounds__(256) void gram_route(
    const float* __restrict__ Gm, float* __restrict__ bws,
    const float* __restrict__ Z, float* __restrict__ Zp)
{
    const int k = blockIdx.x, bb = blockIdx.y;
    const int t = threadIdx.x;
    const int local = k*256 + t;
    const bool valid = local < VSITES;
    float ez8[8];
    #pragma unroll
    for (int D = 0; D < 8; ++D) ez8[D] = 0.f;
    if (valid) {
        const int d  = local / HW;
        const int r2 = local - d*HW;
        float bv[8], cm[8];
        if (ITER == 1) {
            const float inv = 1.0f / (float)(DCAP * HW);
            #pragma unroll
            for (int D = 0; D < 8; ++D) { bv[D] = 0.f; cm[D] = inv; }
        } else {
            #pragma unroll
            for (int D = 0; D < 8; ++D) {
                bv[D] = bws[((size_t)(bb*64 + D*8 + d))*HW + r2];
                cm[D] = expf(bv[D]) * (1.0f / Z[bb*8 + D]);
            }
        }
        float g[36];
        const float4* gp = (const float4*)(Gm + (size_t)(bb*VSITES + local)*36);
        #pragma unroll
        for (int q = 0; q < 9; ++q) {
            float4 v = gp[q];
            g[q*4+0] = v.x; g[q*4+1] = v.y; g[q*4+2] = v.z; g[q*4+3] = v.w;
        }
        float tD[8];
        #pragma unroll
        for (int D = 0; D < 8; ++D) tD[D] = 0.f;
        {
            int idx = 0;
            #pragma unroll
            for (int D = 0; D < 8; ++D)
                #pragma unroll
                for (int Dp = D; Dp < 8; ++Dp) {
                    float gv = g[idx]; ++idx;
                    tD[D] += cm[Dp] * gv;
                    if (Dp != D) tD[Dp] += cm[D] * gv;
                }
        }
        float n2 = 0.f;
        #pragma unroll
        for (int D = 0; D < 8; ++D) n2 += cm[D] * tD[D];
        float fac = (n2 / (1.f + n2)) / sqrtf(n2 + EPSQ);
        #pragma unroll
        for (int D = 0; D < 8; ++D) {
            float nb = bv[D] + fac * tD[D];
            bws[((size_t)(bb*64 + D*8 + d))*HW + r2] = nb;
            ez8[D] = expf(nb);
        }
    }
    // block-reduce 8 per-D sums -> contention-free Zp slot
    #pragma unroll
    for (int D = 0; D < 8; ++D)
        #pragma unroll
        for (int off = 1; off < 64; off <<= 1) ez8[D] += __shfl_xor(ez8[D], off);
    __shared__ float ps[4][8];
    if ((t & 63) == 0) {
        #pragma unroll
        for (int D = 0; D < 8; ++D) ps[t >> 6][D] = ez8[D];
    }
    __syncthreads();
    if (t < 8)
        Zp[((size_t)bb*8 + t)*NBLK2 + k] = ps[0][t] + ps[1][t] + ps[2][t] + ps[3][t];
}

// ---------------------------------------------------------------------------
// r13 pass C: conv + MODE2 epilogue (s output). Same geometry as conv_g.
// Epilogue copied verbatim from the r7-verified MODE2 path.
// ---------------------------------------------------------------------------
__global__ __launch_bounds__(256, 4) void conv_s(
    const ushort* __restrict__ xb,
    const ushort* __restrict__ w_hi, const ushort* __restrict__ w_lo,
    const float* __restrict__ bws, const float* __restrict__ Z,
    float* __restrict__ out)
{
    const int t  = threadIdx.x;
    const int wx = blockIdx.x, h0 = blockIdx.y, bb = blockIdx.z;
    const int w0 = wx*8;

    __shared__ __align__(16) ushort a_hi[64][APAD];  // 21504 B
    __shared__ float  cms[64][8];                    // 2048 B
    __shared__ float  invZ[8];
    __shared__ union {                               // 8192 B
        ushort patchb[CIN][DDEP][3][10];             //   phases 0-1 (7680 B)
        float  sout[256][8];                         //   epilogue
    } ov;

    // ---- phase 0: c-coeffs (from b2, Z2) + bf16 patch ----
    if (t < 8) invZ[t] = 1.0f / Z[64 + bb*8 + t];
    for (int v = t; v < 512; v += 256) {
        int Dd = v >> 3, wi = v & 7;
        int w = w0 + wi;
        float bv = (w < WOUT) ? bws[((size_t)bb*64 + Dd)*HW + (size_t)h0*WOUT + w] : 0.f;
        cms[Dd][wi] = expf(bv);
    }
    for (int i = t; i < CIN*DDEP*3*5; i += 256) {
        int ci = i / 120, rem = i - ci*120;
        int D  = rem / 15, r2 = rem - D*15;
        int kh = r2 / 5, uc = r2 - kh*5;
        int xc = w0 + uc*2;
        const ushort* row = xb + (((size_t)(bb*CIN + ci)*DDEP + D)*HIN + (h0+kh))*WIN;
        unsigned v;
        if (xc + 1 < WIN) v = *(const unsigned*)&row[xc];
        else { unsigned e = row[95]; v = e | (e << 16); }
        *(unsigned*)&ov.patchb[ci][D][kh][uc*2] = v;
    }
    __syncthreads();

    // ---- phase 1: im2col ----
    {
        const int site = t >> 2, kg = t & 3;
        const int D = site >> 3, wi = site & 7;
        #pragma unroll
        for (int u2 = 0; u2 < 18; ++u2) {
            int k0 = kg*36 + u2*2;
            int ci0 = k0/9, r0 = k0 - ci0*9, kh0 = r0/3, kw0 = r0 - kh0*3;
            int k1 = k0 + 1;
            int ci1 = k1/9, r1 = k1 - ci1*9, kh1 = r1/3, kw1 = r1 - kh1*3;
            unsigned lo = ov.patchb[ci0][D][kh0][wi+kw0];
            unsigned hi = ov.patchb[ci1][D][kh1][wi+kw1];
            *(unsigned*)&a_hi[site][k0] = lo | (hi << 16);
        }
        if (t < 64) {
            #pragma unroll
            for (int kk = KTOT; kk < KTILES*32; kk += 2)
                *(unsigned*)&a_hi[t][kk] = 0u;
        }
    }
    __syncthreads();

    // ---- phase 2: MFMA K-loop ----
    const int wv = t >> 6, lane = t & 63;
    const int m16 = lane & 15, quad = lane >> 4;
    f32x4 acc[4][4];
    #pragma unroll
    for (int mt = 0; mt < 4; ++mt)
        #pragma unroll
        for (int nt = 0; nt < 4; ++nt)
            acc[mt][nt] = (f32x4){0.f, 0.f, 0.f, 0.f};

    #pragma unroll
    for (int kt = 0; kt < KTILES; ++kt) {
        bf16x8 ah[4];
        #pragma unroll
        for (int mt = 0; mt < 4; ++mt)
            ah[mt] = *(const bf16x8*)&a_hi[mt*16 + m16][kt*32 + quad*8];
        #pragma unroll
        for (int nt = 0; nt < 4; ++nt) {
            size_t off = (((size_t)kt*16 + (wv*4 + nt))*64 + lane)*8;
            bf16x8 bh = *(const bf16x8*)&w_hi[off];
            bf16x8 bl = *(const bf16x8*)&w_lo[off];
            #pragma unroll
            for (int mt = 0; mt < 4; ++mt) {
                acc[mt][nt] = __builtin_amdgcn_mfma_f32_16x16x32_bf16(ah[mt], bh, acc[mt][nt], 0, 0, 0);
                acc[mt][nt] = __builtin_amdgcn_mfma_f32_16x16x32_bf16(ah[mt], bl, acc[mt][nt], 0, 0, 0);
            }
        }
    }

    // ---- phase 3: s epilogue (verbatim r7-verified MODE2 path) ----
    const int d   = m16 & 7;
    const int Dq  = quad >> 1;
    const int wih = quad & 1;
    float svv[4][4];
    {
        float cmw[4][4];
        #pragma unroll
        for (int mt = 0; mt < 4; ++mt) {
            int D = mt*2 + Dq;
            float iz = invZ[D];
            #pragma unroll
            for (int r = 0; r < 4; ++r) cmw[mt][r] = cms[D*8 + d][wih*4 + r] * iz;
        }
        #pragma unroll
        for (int nt = 0; nt < 4; ++nt)
            #pragma unroll
            for (int r = 0; r < 4; ++r) {
                float partial = 0.f;
                #pragma unroll
                for (int mt = 0; mt < 4; ++mt) partial += cmw[mt][r]*acc[mt][nt][r];
                partial += __shfl_xor(partial, 32);
                svv[nt][r] = partial;   // uniform in lane bit5
            }
    }
    if (quad < 2) {   // one Dq copy per (wih, m16, nt)
        #pragma unroll
        for (int nt = 0; nt < 4; ++nt) {
            int ch = wv*64 + nt*16 + m16;
            #pragma unroll
            for (int r = 0; r < 4; ++r) ov.sout[ch][wih*4 + r] = svv[nt][r];
        }
    }
    __syncthreads();
    for (int i = t; i < 1024; i += 256) {
        int c2 = i >> 2, wip = i & 3;
        int w = w0 + wip*2;
        if (w + 1 < WOUT) {
            float2 v2 = { ov.sout[c2][wip*2], ov.sout[c2][wip*2 + 1] };
            *(float2*)&out[((size_t)bb*CH + c2)*HW + (size_t)h0*WOUT + w] = v2;
        }
    }
}

// ---------------------------------------------------------------------------
// Workspace (~119 MB total; ws >= 213 MB proven in r11 — single path):
//   bws 18.1 | Z 512B | Zp 70KB | wfrags 320KB | xb 18.9 | Gm 81.4
// ---------------------------------------------------------------------------
extern "C" void kernel_launch(void* const* d_in, const int* in_sizes, int n_in,
                              void* d_out, int out_size, void* d_ws, size_t ws_size,
                              hipStream_t stream)
{
    (void)in_sizes; (void)n_in; (void)out_size; (void)ws_size;
    const float* x     = (const float*)d_in[0];
    const float* wconv = (const float*)d_in[1];
    float* out = (float*)d_out;

    float*  bws  = (float*)d_ws;
    float*  Z    = bws + B_ELEMS;            // Z1 = Z[0..63], Z2 = Z[64..127]
    float*  Zp   = Z + 128;                  // 64*NBLK2 partials
    ushort* w_hi = (ushort*)(Zp + 64*NBLK2);
    ushort* w_lo = w_hi + WFRAG_ELEMS;
    ushort* xb   = w_lo + WFRAG_ELEMS;       // bf16 x cache
    size_t  base = (size_t)((char*)(xb + XN) - (char*)d_ws);
    size_t  goff = (base + 255) & ~(size_t)255;
    float*  Gm   = (float*)((char*)d_ws + goff);

    const dim3 grid(12, 94, 8);
    build_wfrag<<<dim3(16, KTILES), 64, 0, stream>>>(wconv, w_hi, w_lo);
    xconvert<<<(unsigned)(XN/4/256), 256, 0, stream>>>(x, xb);
    conv_g<<<grid, 256, 0, stream>>>(xb, w_hi, w_lo, Gm);
    gram_route<1><<<dim3(NBLK2, 8), 256, 0, stream>>>(Gm, bws, Z, Zp);
    zreduce<<<64, 256, 0, stream>>>(Zp, Z, 0, NBLK2);
    gram_route<2><<<dim3(NBLK2, 8), 256, 0, stream>>>(Gm, bws, Z, Zp);
    zreduce<<<64, 256, 0, stream>>>(Zp, Z, 64, NBLK2);
    conv_s<<<grid, 256, 0, stream>>>(xb, w_hi, w_lo, bws, Z, out);
}

// Round 5
// 1370.886 us; speedup vs baseline: 1.0221x; 1.0221x over previous
//
#include <hip/hip_runtime.h>
#include <math.h>

#define CIN   16
#define DDEP  8      // conv depth (routing "D")
#define HIN   96
#define WIN   96
#define HOUT  94
#define WOUT  94
#define HW    (HOUT*WOUT)        // 8836
#define CH    256                 // out channels = c*8+d
#define DCAP  8
#define KTOT  (CIN*9)             // 144
#define KTILES 5                  // K padded to 160
#define APAD  168                 // A row stride (bf16 elems)
#define EPSQ  1e-8f

#define B_ELEMS ((size_t)8*DDEP*DCAP*HW)          // 4,524,032 floats
#define WFRAG_ELEMS ((size_t)KTILES*16*64*8)      // 40,960 per half
#define VSITES (DCAP*HW)                          // 70,688 sites per batch
#define NBLK2  277                                // ceil(70688/256)
#define XN ((size_t)8*CIN*DDEP*HIN*WIN)           // 9,437,184 x elems
#define G_BYTES ((size_t)8*VSITES*36*4)           // 81,432,576 B

typedef __attribute__((ext_vector_type(8))) short bf16x8;
typedef __attribute__((ext_vector_type(4))) float f32x4;

// explicit RNE float->bf16 bit conversion
__device__ __forceinline__ ushort f2bf(float f) {
    unsigned u = __float_as_uint(f);
    return (ushort)((u + 0x7FFFu + ((u >> 16) & 1u)) >> 16);
}
__device__ __forceinline__ float bf2f(ushort h) {
    return __uint_as_float(((unsigned)h) << 16);
}

// ---------------------------------------------------------------------------
// W -> MFMA B-fragment order, hi/lo split. frag[kt][nt][lane][j] = W[k][n],
// k = kt*32 + (lane>>4)*8 + j (0 for k>=144), n = nt*16 + (lane&15).
// ---------------------------------------------------------------------------
__global__ __launch_bounds__(64) void build_wfrag(
    const float* __restrict__ w, ushort* __restrict__ w_hi, ushort* __restrict__ w_lo)
{
    const int lane = threadIdx.x;
    const int nt = blockIdx.x, kt = blockIdx.y;
    const int n  = nt*16 + (lane & 15);
    const int kb = kt*32 + (lane >> 4)*8;
    size_t off = (((size_t)kt*16 + nt)*64 + lane)*8;
    for (int j = 0; j < 8; ++j) {
        int k = kb + j;
        float v = (k < KTOT) ? w[(size_t)n*KTOT + k] : 0.f;
        ushort hi = f2bf(v);
        float  r  = v - bf2f(hi);
        ushort lo = f2bf(r);
        w_hi[off + j] = hi; w_lo[off + j] = lo;
    }
}

// ---------------------------------------------------------------------------
// r13: one-shot x -> bf16 side-cache (18.9 MB). Both conv passes stage ushort
// patches from this (identical bits to in-pass f2bf -> bitwise-same A tiles).
// ---------------------------------------------------------------------------
__global__ __launch_bounds__(256) void xconvert(
    const float* __restrict__ x, ushort* __restrict__ xb)
{
    size_t i = (size_t)blockIdx.x*256 + threadIdx.x;
    if (i*4 >= XN) return;
    float4 v = ((const float4*)x)[i];
    ushort4 o;
    o.x = f2bf(v.x); o.y = f2bf(v.y); o.z = f2bf(v.z); o.w = f2bf(v.w);
    ((ushort4*)xb)[i] = o;
}

// ---------------------------------------------------------------------------
// Z reduce from contention-free per-block partials (r10 lesson: NEVER funnel
// per-block Z through same-address device atomics — serialized ~+120us/pass).
// ---------------------------------------------------------------------------
__global__ __launch_bounds__(256) void zreduce(
    const float* __restrict__ Zp, float* __restrict__ Z, int dst, int count)
{
    const int bd = blockIdx.x;
    const float* p = Zp + (size_t)bd * count;
    float s = 0.f;
    for (int i = threadIdx.x; i < count; i += 256) s += p[i];
    #pragma unroll
    for (int off = 1; off < 64; off <<= 1) s += __shfl_xor(s, off);
    __shared__ float ps[4];
    if ((threadIdx.x & 63) == 0) ps[threadIdx.x >> 6] = s;
    __syncthreads();
    if (threadIdx.x == 0) Z[dst + bd] = ps[0] + ps[1] + ps[2] + ps[3];
}

// ---------------------------------------------------------------------------
// Pass A: implicit-GEMM MFMA conv -> per-site 8x8 Gram matrix ONLY.
// Block: (wx,h0,bb) -> 8 D x 1 h-row x 8 w; M=64, N=256.
// acc[mt][nt][r]: m = mt*16 + quad*4 + r -> D = mt*2 + (quad>>1),
//                 wi = (quad&1)*4 + r;  ch = wv*64 + nt*16 + m16.
// G_DD'(d,wi) = sum_c u_cD*u_cD' (36 sym entries).
// r12 lesson (rule #20): NO runtime-indexed register arrays — u8 fill uses
// cndmask selects with static indices.
// r13 lesson (NEW, critical): __launch_bounds__ min-waves arg caps the
// UNIFIED reg file. At (256,4) the cap is 128 = acc-in-AGPR(64) + 64 VGPRs
// exactly -> G36[36] spilled to scratch -> 1.9 GB HBM writes, 5x slowdown.
// KEEP (256,2) on any kernel holding acc + extra live arrays.
// ---------------------------------------------------------------------------
__global__ __launch_bounds__(256, 2) void conv_g(
    const ushort* __restrict__ xb,
    const ushort* __restrict__ w_hi, const ushort* __restrict__ w_lo,
    float* __restrict__ Gm)
{
    const int t  = threadIdx.x;
    const int wx = blockIdx.x, h0 = blockIdx.y, bb = blockIdx.z;
    const int w0 = wx*8;

    __shared__ __align__(16) ushort a_hi[64][APAD];  // 21504 B (all phases)
    __shared__ union {                               // 18432 B, lifetime-disjoint
        ushort patchb[CIN][DDEP][3][10];             //   phases 0-1 (7680 B)
        float  gst[2][4][16][36];                    //   Gram staging (post-MFMA)
    } ov;

    // ---- phase 0: stage bf16 x patch (uint pair loads, clamped tail) ----
    for (int i = t; i < CIN*DDEP*3*5; i += 256) {
        int ci = i / 120, rem = i - ci*120;
        int D  = rem / 15, r2 = rem - D*15;
        int kh = r2 / 5, uc = r2 - kh*5;
        int xc = w0 + uc*2;
        const ushort* row = xb + (((size_t)(bb*CIN + ci)*DDEP + D)*HIN + (h0+kh))*WIN;
        unsigned v;
        if (xc + 1 < WIN) v = *(const unsigned*)&row[xc];
        else { unsigned e = row[95]; v = e | (e << 16); }  // clamp: garbage cols feed only invalid sites
        *(unsigned*)&ov.patchb[ci][D][kh][uc*2] = v;
    }
    __syncthreads();

    // ---- phase 1: im2col (pure ushort packing; no f2bf) ----
    {
        const int site = t >> 2, kg = t & 3;     // site = D*8 + wi
        const int D = site >> 3, wi = site & 7;
        #pragma unroll
        for (int u2 = 0; u2 < 18; ++u2) {
            int k0 = kg*36 + u2*2;
            int ci0 = k0/9, r0 = k0 - ci0*9, kh0 = r0/3, kw0 = r0 - kh0*3;
            int k1 = k0 + 1;
            int ci1 = k1/9, r1 = k1 - ci1*9, kh1 = r1/3, kw1 = r1 - kh1*3;
            unsigned lo = ov.patchb[ci0][D][kh0][wi+kw0];
            unsigned hi = ov.patchb[ci1][D][kh1][wi+kw1];
            *(unsigned*)&a_hi[site][k0] = lo | (hi << 16);
        }
        if (t < 64) {
            #pragma unroll
            for (int kk = KTOT; kk < KTILES*32; kk += 2)
                *(unsigned*)&a_hi[t][kk] = 0u;
        }
    }
    __syncthreads();

    // ---- phase 2: MFMA K-loop ----
    const int wv = t >> 6, lane = t & 63;
    const int m16 = lane & 15, quad = lane >> 4;
    const int Dq = quad >> 1, wih = quad & 1;
    f32x4 acc[4][4];
    #pragma unroll
    for (int mt = 0; mt < 4; ++mt)
        #pragma unroll
        for (int nt = 0; nt < 4; ++nt)
            acc[mt][nt] = (f32x4){0.f, 0.f, 0.f, 0.f};

    #pragma unroll
    for (int kt = 0; kt < KTILES; ++kt) {
        bf16x8 ah[4];
        #pragma unroll
        for (int mt = 0; mt < 4; ++mt)
            ah[mt] = *(const bf16x8*)&a_hi[mt*16 + m16][kt*32 + quad*8];
        #pragma unroll
        for (int nt = 0; nt < 4; ++nt) {
            size_t off = (((size_t)kt*16 + (wv*4 + nt))*64 + lane)*8;
            bf16x8 bh = *(const bf16x8*)&w_hi[off];
            bf16x8 bl = *(const bf16x8*)&w_lo[off];
            #pragma unroll
            for (int mt = 0; mt < 4; ++mt) {
                acc[mt][nt] = __builtin_amdgcn_mfma_f32_16x16x32_bf16(ah[mt], bh, acc[mt][nt], 0, 0, 0);
                acc[mt][nt] = __builtin_amdgcn_mfma_f32_16x16x32_bf16(ah[mt], bl, acc[mt][nt], 0, 0, 0);
            }
        }
    }

    // ---- phase 3: Gram (2-r batches, 3 barriers; all-lane, scratch-free) ----
    const int dL = m16 & 7;
    #pragma unroll
    for (int rp = 0; rp < 2; ++rp) {
        #pragma unroll
        for (int rb = 0; rb < 2; ++rb) {
            const int r = rp*2 + rb;
            float G36[36];
            #pragma unroll
            for (int j = 0; j < 36; ++j) G36[j] = 0.f;
            #pragma unroll
            for (int nt = 0; nt < 4; ++nt) {
                float u8[8];
                #pragma unroll
                for (int mt = 0; mt < 4; ++mt) {
                    float own = acc[mt][nt][r];
                    float oth = __shfl_xor(own, 32);
                    u8[mt*2]     = (Dq == 0) ? own : oth;   // D = mt*2
                    u8[mt*2 + 1] = (Dq == 0) ? oth : own;   // D = mt*2+1
                }
                int idx = 0;
                #pragma unroll
                for (int D = 0; D < 8; ++D)
                    #pragma unroll
                    for (int Dp = D; Dp < 8; ++Dp) {
                        G36[idx] += u8[D]*u8[Dp];
                        ++idx;
                    }
            }
            #pragma unroll
            for (int j = 0; j < 36; ++j) G36[j] += __shfl_xor(G36[j], 8);
            if (Dq == 0 && m16 < 8) {
                #pragma unroll
                for (int j = 0; j < 36; ++j) ov.gst[rb][wv][dL*2 + wih][j] = G36[j];
            }
        }
        __syncthreads();
        // cross-wave sum + global write: 2 x 16 sites x 36, 144B runs/site
        for (int idx2 = t; idx2 < 2*16*36; idx2 += 256) {
            int rb = idx2 / 576, rem = idx2 - rb*576;
            int sidx = rem / 36, j = rem - sidx*36;
            int dd = sidx >> 1, wh = sidx & 1;
            int w = w0 + wh*4 + rp*2 + rb;
            if (w < WOUT) {
                float gv = ov.gst[rb][0][sidx][j] + ov.gst[rb][1][sidx][j]
                         + ov.gst[rb][2][sidx][j] + ov.gst[rb][3][sidx][j];
                size_t gsite = ((size_t)(bb*DCAP + dd)*HOUT + h0)*WOUT + w;
                Gm[gsite*36 + j] = gv;
            }
        }
        if (rp == 0) __syncthreads();
    }
}

// ---------------------------------------------------------------------------
// Routing iterations 1 AND 2 from the Gram matrix (both pure streaming).
// ITER 1: cm uniform (b0=0), b1 = fac*(G cm), Z1 partials.
// ITER 2: cm = exp(b1)/Z1, b2 = b1 + fac*(G cm), Z2 partials.
// gram iter2 path validated on-harness in r12 (passed, absmax unchanged).
// ---------------------------------------------------------------------------
template<int ITER>
__global__ __launch_bounds__(256) void gram_route(
    const float* __restrict__ Gm, float* __restrict__ bws,
    const float* __restrict__ Z, float* __restrict__ Zp)
{
    const int k = blockIdx.x, bb = blockIdx.y;
    const int t = threadIdx.x;
    const int local = k*256 + t;
    const bool valid = local < VSITES;
    float ez8[8];
    #pragma unroll
    for (int D = 0; D < 8; ++D) ez8[D] = 0.f;
    if (valid) {
        const int d  = local / HW;
        const int r2 = local - d*HW;
        float bv[8], cm[8];
        if (ITER == 1) {
            const float inv = 1.0f / (float)(DCAP * HW);
            #pragma unroll
            for (int D = 0; D < 8; ++D) { bv[D] = 0.f; cm[D] = inv; }
        } else {
            #pragma unroll
            for (int D = 0; D < 8; ++D) {
                bv[D] = bws[((size_t)(bb*64 + D*8 + d))*HW + r2];
                cm[D] = expf(bv[D]) * (1.0f / Z[bb*8 + D]);
            }
        }
        float g[36];
        const float4* gp = (const float4*)(Gm + (size_t)(bb*VSITES + local)*36);
        #pragma unroll
        for (int q = 0; q < 9; ++q) {
            float4 v = gp[q];
            g[q*4+0] = v.x; g[q*4+1] = v.y; g[q*4+2] = v.z; g[q*4+3] = v.w;
        }
        float tD[8];
        #pragma unroll
        for (int D = 0; D < 8; ++D) tD[D] = 0.f;
        {
            int idx = 0;
            #pragma unroll
            for (int D = 0; D < 8; ++D)
                #pragma unroll
                for (int Dp = D; Dp < 8; ++Dp) {
                    float gv = g[idx]; ++idx;
                    tD[D] += cm[Dp] * gv;
                    if (Dp != D) tD[Dp] += cm[D] * gv;
                }
        }
        float n2 = 0.f;
        #pragma unroll
        for (int D = 0; D < 8; ++D) n2 += cm[D] * tD[D];
        float fac = (n2 / (1.f + n2)) / sqrtf(n2 + EPSQ);
        #pragma unroll
        for (int D = 0; D < 8; ++D) {
            float nb = bv[D] + fac * tD[D];
            bws[((size_t)(bb*64 + D*8 + d))*HW + r2] = nb;
            ez8[D] = expf(nb);
        }
    }
    // block-reduce 8 per-D sums -> contention-free Zp slot
    #pragma unroll
    for (int D = 0; D < 8; ++D)
        #pragma unroll
        for (int off = 1; off < 64; off <<= 1) ez8[D] += __shfl_xor(ez8[D], off);
    __shared__ float ps[4][8];
    if ((t & 63) == 0) {
        #pragma unroll
        for (int D = 0; D < 8; ++D) ps[t >> 6][D] = ez8[D];
    }
    __syncthreads();
    if (t < 8)
        Zp[((size_t)bb*8 + t)*NBLK2 + k] = ps[0][t] + ps[1][t] + ps[2][t] + ps[3][t];
}

// ---------------------------------------------------------------------------
// Pass C: conv + MODE2 epilogue (s output). Same geometry as conv_g.
// Epilogue copied verbatim from the r7-verified MODE2 path. (256,2) — see
// the r13 launch-bounds lesson in conv_g's header.
// ---------------------------------------------------------------------------
__global__ __launch_bounds__(256, 2) void conv_s(
    const ushort* __restrict__ xb,
    const ushort* __restrict__ w_hi, const ushort* __restrict__ w_lo,
    const float* __restrict__ bws, const float* __restrict__ Z,
    float* __restrict__ out)
{
    const int t  = threadIdx.x;
    const int wx = blockIdx.x, h0 = blockIdx.y, bb = blockIdx.z;
    const int w0 = wx*8;

    __shared__ __align__(16) ushort a_hi[64][APAD];  // 21504 B
    __shared__ float  cms[64][8];                    // 2048 B
    __shared__ float  invZ[8];
    __shared__ union {                               // 8192 B
        ushort patchb[CIN][DDEP][3][10];             //   phases 0-1 (7680 B)
        float  sout[256][8];                         //   epilogue
    } ov;

    // ---- phase 0: c-coeffs (from b2, Z2) + bf16 patch ----
    if (t < 8) invZ[t] = 1.0f / Z[64 + bb*8 + t];
    for (int v = t; v < 512; v += 256) {
        int Dd = v >> 3, wi = v & 7;
        int w = w0 + wi;
        float bv = (w < WOUT) ? bws[((size_t)bb*64 + Dd)*HW + (size_t)h0*WOUT + w] : 0.f;
        cms[Dd][wi] = expf(bv);
    }
    for (int i = t; i < CIN*DDEP*3*5; i += 256) {
        int ci = i / 120, rem = i - ci*120;
        int D  = rem / 15, r2 = rem - D*15;
        int kh = r2 / 5, uc = r2 - kh*5;
        int xc = w0 + uc*2;
        const ushort* row = xb + (((size_t)(bb*CIN + ci)*DDEP + D)*HIN + (h0+kh))*WIN;
        unsigned v;
        if (xc + 1 < WIN) v = *(const unsigned*)&row[xc];
        else { unsigned e = row[95]; v = e | (e << 16); }
        *(unsigned*)&ov.patchb[ci][D][kh][uc*2] = v;
    }
    __syncthreads();

    // ---- phase 1: im2col ----
    {
        const int site = t >> 2, kg = t & 3;
        const int D = site >> 3, wi = site & 7;
        #pragma unroll
        for (int u2 = 0; u2 < 18; ++u2) {
            int k0 = kg*36 + u2*2;
            int ci0 = k0/9, r0 = k0 - ci0*9, kh0 = r0/3, kw0 = r0 - kh0*3;
            int k1 = k0 + 1;
            int ci1 = k1/9, r1 = k1 - ci1*9, kh1 = r1/3, kw1 = r1 - kh1*3;
            unsigned lo = ov.patchb[ci0][D][kh0][wi+kw0];
            unsigned hi = ov.patchb[ci1][D][kh1][wi+kw1];
            *(unsigned*)&a_hi[site][k0] = lo | (hi << 16);
        }
        if (t < 64) {
            #pragma unroll
            for (int kk = KTOT; kk < KTILES*32; kk += 2)
                *(unsigned*)&a_hi[t][kk] = 0u;
        }
    }
    __syncthreads();

    // ---- phase 2: MFMA K-loop ----
    const int wv = t >> 6, lane = t & 63;
    const int m16 = lane & 15, quad = lane >> 4;
    f32x4 acc[4][4];
    #pragma unroll
    for (int mt = 0; mt < 4; ++mt)
        #pragma unroll
        for (int nt = 0; nt < 4; ++nt)
            acc[mt][nt] = (f32x4){0.f, 0.f, 0.f, 0.f};

    #pragma unroll
    for (int kt = 0; kt < KTILES; ++kt) {
        bf16x8 ah[4];
        #pragma unroll
        for (int mt = 0; mt < 4; ++mt)
            ah[mt] = *(const bf16x8*)&a_hi[mt*16 + m16][kt*32 + quad*8];
        #pragma unroll
        for (int nt = 0; nt < 4; ++nt) {
            size_t off = (((size_t)kt*16 + (wv*4 + nt))*64 + lane)*8;
            bf16x8 bh = *(const bf16x8*)&w_hi[off];
            bf16x8 bl = *(const bf16x8*)&w_lo[off];
            #pragma unroll
            for (int mt = 0; mt < 4; ++mt) {
                acc[mt][nt] = __builtin_amdgcn_mfma_f32_16x16x32_bf16(ah[mt], bh, acc[mt][nt], 0, 0, 0);
                acc[mt][nt] = __builtin_amdgcn_mfma_f32_16x16x32_bf16(ah[mt], bl, acc[mt][nt], 0, 0, 0);
            }
        }
    }

    // ---- phase 3: s epilogue (verbatim r7-verified MODE2 path) ----
    const int d   = m16 & 7;
    const int Dq  = quad >> 1;
    const int wih = quad & 1;
    float svv[4][4];
    {
        float cmw[4][4];
        #pragma unroll
        for (int mt = 0; mt < 4; ++mt) {
            int D = mt*2 + Dq;
            float iz = invZ[D];
            #pragma unroll
            for (int r = 0; r < 4; ++r) cmw[mt][r] = cms[D*8 + d][wih*4 + r] * iz;
        }
        #pragma unroll
        for (int nt = 0; nt < 4; ++nt)
            #pragma unroll
            for (int r = 0; r < 4; ++r) {
                float partial = 0.f;
                #pragma unroll
                for (int mt = 0; mt < 4; ++mt) partial += cmw[mt][r]*acc[mt][nt][r];
                partial += __shfl_xor(partial, 32);
                svv[nt][r] = partial;   // uniform in lane bit5
            }
    }
    if (quad < 2) {   // one Dq copy per (wih, m16, nt)
        #pragma unroll
        for (int nt = 0; nt < 4; ++nt) {
            int ch = wv*64 + nt*16 + m16;
            #pragma unroll
            for (int r = 0; r < 4; ++r) ov.sout[ch][wih*4 + r] = svv[nt][r];
        }
    }
    __syncthreads();
    for (int i = t; i < 1024; i += 256) {
        int c2 = i >> 2, wip = i & 3;
        int w = w0 + wip*2;
        if (w + 1 < WOUT) {
            float2 v2 = { ov.sout[c2][wip*2], ov.sout[c2][wip*2 + 1] };
            *(float2*)&out[((size_t)bb*CH + c2)*HW + (size_t)h0*WOUT + w] = v2;
        }
    }
}

// ---------------------------------------------------------------------------
// Workspace (~119 MB total; ws >= 213 MB proven in r11 — single path):
//   bws 18.1 | Z 512B | Zp 70KB | wfrags 320KB | xb 18.9 | Gm 81.4
// ---------------------------------------------------------------------------
extern "C" void kernel_launch(void* const* d_in, const int* in_sizes, int n_in,
                              void* d_out, int out_size, void* d_ws, size_t ws_size,
                              hipStream_t stream)
{
    (void)in_sizes; (void)n_in; (void)out_size; (void)ws_size;
    const float* x     = (const float*)d_in[0];
    const float* wconv = (const float*)d_in[1];
    float* out = (float*)d_out;

    float*  bws  = (float*)d_ws;
    float*  Z    = bws + B_ELEMS;            // Z1 = Z[0..63], Z2 = Z[64..127]
    float*  Zp   = Z + 128;                  // 64*NBLK2 partials
    ushort* w_hi = (ushort*)(Zp + 64*NBLK2);
    ushort* w_lo = w_hi + WFRAG_ELEMS;
    ushort* xb   = w_lo + WFRAG_ELEMS;       // bf16 x cache
    size_t  base = (size_t)((char*)(xb + XN) - (char*)d_ws);
    size_t  goff = (base + 255) & ~(size_t)255;
    float*  Gm   = (float*)((char*)d_ws + goff);

    const dim3 grid(12, 94, 8);
    build_wfrag<<<dim3(16, KTILES), 64, 0, stream>>>(wconv, w_hi, w_lo);
    xconvert<<<(unsigned)(XN/4/256), 256, 0, stream>>>(x, xb);
    conv_g<<<grid, 256, 0, stream>>>(xb, w_hi, w_lo, Gm);
    gram_route<1><<<dim3(NBLK2, 8), 256, 0, stream>>>(Gm, bws, Z, Zp);
    zreduce<<<64, 256, 0, stream>>>(Zp, Z, 0, NBLK2);
    gram_route<2><<<dim3(NBLK2, 8), 256, 0, stream>>>(Gm, bws, Z, Zp);
    zreduce<<<64, 256, 0, stream>>>(Zp, Z, 64, NBLK2);
    conv_s<<<grid, 256, 0, stream>>>(xb, w_hi, w_lo, bws, Z, out);
}

// Round 8
// 576.344 us; speedup vs baseline: 2.4311x; 2.3786x over previous
//
#include <hip/hip_runtime.h>
#include <math.h>

#define CIN   16
#define DDEP  8      // conv depth (routing "D")
#define HIN   96
#define WIN   96
#define HOUT  94
#define WOUT  94
#define HW    (HOUT*WOUT)        // 8836
#define CH    256                 // out channels = c*8+d
#define DCAP  8
#define KTOT  (CIN*9)             // 144
#define KTILES 5                  // K padded to 160
#define APAD  168                 // A row stride (bf16 elems)
#define EPSQ  1e-8f

#define B_ELEMS ((size_t)8*DDEP*DCAP*HW)          // 4,524,032 floats
#define WFRAG_ELEMS ((size_t)KTILES*16*64*8)      // 40,960 per half
#define BLK_PER_B (94*12)                         // 1128 spatial blocks/batch
#define VSITES (DCAP*HW)                          // 70,688 sites per batch
#define NBLK2  277                                // ceil(70688/256)
#define XN ((size_t)8*CIN*DDEP*HIN*WIN)           // 9,437,184 x elems
#define G_BYTES ((size_t)8*VSITES*36*4)           // 81,432,576 B

typedef __attribute__((ext_vector_type(8))) short bf16x8;
typedef __attribute__((ext_vector_type(4))) float f32x4;

// explicit RNE float->bf16 bit conversion
__device__ __forceinline__ ushort f2bf(float f) {
    unsigned u = __float_as_uint(f);
    return (ushort)((u + 0x7FFFu + ((u >> 16) & 1u)) >> 16);
}
__device__ __forceinline__ float bf2f(ushort h) {
    return __uint_as_float(((unsigned)h) << 16);
}

// ---------------------------------------------------------------------------
// W -> MFMA B-fragment order, hi/lo split. frag[kt][nt][lane][j] = W[k][n],
// k = kt*32 + (lane>>4)*8 + j (0 for k>=144), n = nt*16 + (lane&15).
// ---------------------------------------------------------------------------
__global__ __launch_bounds__(64) void build_wfrag(
    const float* __restrict__ w, ushort* __restrict__ w_hi, ushort* __restrict__ w_lo)
{
    const int lane = threadIdx.x;
    const int nt = blockIdx.x, kt = blockIdx.y;
    const int n  = nt*16 + (lane & 15);
    const int kb = kt*32 + (lane >> 4)*8;
    size_t off = (((size_t)kt*16 + nt)*64 + lane)*8;
    for (int j = 0; j < 8; ++j) {
        int k = kb + j;
        float v = (k < KTOT) ? w[(size_t)n*KTOT + k] : 0.f;
        ushort hi = f2bf(v);
        float  r  = v - bf2f(hi);
        ushort lo = f2bf(r);
        w_hi[off + j] = hi; w_lo[off + j] = lo;
    }
}

// ---------------------------------------------------------------------------
// One-shot x -> bf16 side-cache (18.9 MB). Conv passes stage ushort patches
// from this (identical bits to in-pass f2bf -> bitwise-same A tiles).
// ---------------------------------------------------------------------------
__global__ __launch_bounds__(256) void xconvert(
    const float* __restrict__ x, ushort* __restrict__ xb)
{
    size_t i = (size_t)blockIdx.x*256 + threadIdx.x;
    if (i*4 >= XN) return;
    float4 v = ((const float4*)x)[i];
    ushort4 o;
    o.x = f2bf(v.x); o.y = f2bf(v.y); o.z = f2bf(v.z); o.w = f2bf(v.w);
    ((ushort4*)xb)[i] = o;
}

// ---------------------------------------------------------------------------
// Z reduce from contention-free per-block partials (r10 lesson: NEVER funnel
// per-block Z through same-address device atomics — serialized ~+120us/pass).
// ---------------------------------------------------------------------------
__global__ __launch_bounds__(256) void zreduce(
    const float* __restrict__ Zp, float* __restrict__ Z, int dst, int count)
{
    const int bd = blockIdx.x;
    const float* p = Zp + (size_t)bd * count;
    float s = 0.f;
    for (int i = threadIdx.x; i < count; i += 256) s += p[i];
    #pragma unroll
    for (int off = 1; off < 64; off <<= 1) s += __shfl_xor(s, off);
    __shared__ float ps[4];
    if ((threadIdx.x & 63) == 0) ps[threadIdx.x >> 6] = s;
    __syncthreads();
    if (threadIdx.x == 0) Z[dst + bd] = ps[0] + ps[1] + ps[2] + ps[3];
}

// ---------------------------------------------------------------------------
// Pass A: conv + iter1 (MODE0) epilogue + Gram write.
// Block: (wx,h0,bb) -> 8 D x 1 h-row x 8 w; M=64, N=256.
// acc[mt][nt][r]: m = mt*16 + quad*4 + r -> D = mt*2 + (quad>>1),
//                 wi = (quad&1)*4 + r;  ch = wv*64 + nt*16 + m16; d = m16&7.
// Epilogue: verbatim r7-verified MODE0 path (writes b1 + Z1 partials).
// GW phase: VERBATIM r12 form (per-r barrier loop, Dq==rq half-lane guard) —
// measured no-spill (r12: 355us, WRITE 113MB). r13/r14 lesson: the all-lane
// 2-r-batched rewrite spilled ~130 regs/thread (1.2GB writes, 3x slower);
// the per-r barriers/guards are what bound liveness. DO NOT restructure GW.
// r13 lesson stands too: keep __launch_bounds__(256,2).
// ---------------------------------------------------------------------------
__global__ __launch_bounds__(256, 2) void conv_ag(
    const ushort* __restrict__ xb,
    const ushort* __restrict__ w_hi, const ushort* __restrict__ w_lo,
    float* __restrict__ bws, float* __restrict__ Zp, float* __restrict__ Gm)
{
    const int t  = threadIdx.x;
    const int wx = blockIdx.x, h0 = blockIdx.y, bb = blockIdx.z;
    const int w0 = wx*8;

    __shared__ __align__(16) ushort a_hi[64][APAD];  // 21504 B (all phases)
    __shared__ union {                               // 9216 B, lifetime-disjoint
        ushort patchb[CIN][DDEP][3][10];             //   phases 0-1 (7680 B)
        struct { float n2s[4][8][8];                 //   epilogue
                 float dbs[4][8][8][8]; } ep;
        float gst[4][16][36];                        //   Gram staging (post-ep)
    } ov;

    // ---- phase 0: stage bf16 x patch (uint pair loads, clamped tail) ----
    for (int i = t; i < CIN*DDEP*3*5; i += 256) {
        int ci = i / 120, rem = i - ci*120;
        int D  = rem / 15, r2 = rem - D*15;
        int kh = r2 / 5, uc = r2 - kh*5;
        int xc = w0 + uc*2;
        const ushort* row = xb + (((size_t)(bb*CIN + ci)*DDEP + D)*HIN + (h0+kh))*WIN;
        unsigned v;
        if (xc + 1 < WIN) v = *(const unsigned*)&row[xc];
        else { unsigned e = row[95]; v = e | (e << 16); }  // clamp: garbage cols feed only invalid sites
        *(unsigned*)&ov.patchb[ci][D][kh][uc*2] = v;
    }
    __syncthreads();

    // ---- phase 1: im2col (pure ushort packing; no f2bf) ----
    {
        const int site = t >> 2, kg = t & 3;     // site = D*8 + wi
        const int D = site >> 3, wi = site & 7;
        #pragma unroll
        for (int u2 = 0; u2 < 18; ++u2) {
            int k0 = kg*36 + u2*2;
            int ci0 = k0/9, r0 = k0 - ci0*9, kh0 = r0/3, kw0 = r0 - kh0*3;
            int k1 = k0 + 1;
            int ci1 = k1/9, r1 = k1 - ci1*9, kh1 = r1/3, kw1 = r1 - kh1*3;
            unsigned lo = ov.patchb[ci0][D][kh0][wi+kw0];
            unsigned hi = ov.patchb[ci1][D][kh1][wi+kw1];
            *(unsigned*)&a_hi[site][k0] = lo | (hi << 16);
        }
        if (t < 64) {
            #pragma unroll
            for (int kk = KTOT; kk < KTILES*32; kk += 2)
                *(unsigned*)&a_hi[t][kk] = 0u;
        }
    }
    __syncthreads();

    // ---- phase 2: MFMA K-loop ----
    const int wv = t >> 6, lane = t & 63;
    const int m16 = lane & 15, quad = lane >> 4;
    const int d   = m16 & 7;
    const int Dq  = quad >> 1;      // D parity bit (lane bit5)
    const int wih = quad & 1;       // wi half (lane bit4)
    f32x4 acc[4][4];
    #pragma unroll
    for (int mt = 0; mt < 4; ++mt)
        #pragma unroll
        for (int nt = 0; nt < 4; ++nt)
            acc[mt][nt] = (f32x4){0.f, 0.f, 0.f, 0.f};

    #pragma unroll
    for (int kt = 0; kt < KTILES; ++kt) {
        bf16x8 ah[4];
        #pragma unroll
        for (int mt = 0; mt < 4; ++mt)
            ah[mt] = *(const bf16x8*)&a_hi[mt*16 + m16][kt*32 + quad*8];
        #pragma unroll
        for (int nt = 0; nt < 4; ++nt) {
            size_t off = (((size_t)kt*16 + (wv*4 + nt))*64 + lane)*8;
            bf16x8 bh = *(const bf16x8*)&w_hi[off];
            bf16x8 bl = *(const bf16x8*)&w_lo[off];
            #pragma unroll
            for (int mt = 0; mt < 4; ++mt) {
                acc[mt][nt] = __builtin_amdgcn_mfma_f32_16x16x32_bf16(ah[mt], bh, acc[mt][nt], 0, 0, 0);
                acc[mt][nt] = __builtin_amdgcn_mfma_f32_16x16x32_bf16(ah[mt], bl, acc[mt][nt], 0, 0, 0);
            }
        }
    }

    // ---- phase 3: MODE0 epilogue (verbatim r7-verified; cm uniform) ----
    float svv[4][4];
    {
        const float inv = 1.0f / (float)(DCAP * HW);
        #pragma unroll
        for (int nt = 0; nt < 4; ++nt)
            #pragma unroll
            for (int r = 0; r < 4; ++r) {
                float partial = 0.f;
                #pragma unroll
                for (int mt = 0; mt < 4; ++mt) partial += inv*acc[mt][nt][r];
                partial += __shfl_xor(partial, 32);
                svv[nt][r] = partial;   // uniform in lane bit5
            }
    }
    // n2(d,wi) = sum_c sv^2 : reg-sum over nt + shfl_xor(8) + cross-wave LDS
    float p2[4];
    #pragma unroll
    for (int r = 0; r < 4; ++r) {
        float s2 = 0.f;
        #pragma unroll
        for (int nt = 0; nt < 4; ++nt) s2 += svv[nt][r]*svv[nt][r];
        p2[r] = s2;
    }
    #pragma unroll
    for (int r = 0; r < 4; ++r) p2[r] += __shfl_xor(p2[r], 8);
    if (quad < 2 && m16 < 8) {
        #pragma unroll
        for (int r = 0; r < 4; ++r) ov.ep.n2s[wv][m16][quad*4 + r] = p2[r];
    }
    __syncthreads();
    float fac[4];
    #pragma unroll
    for (int r = 0; r < 4; ++r) {
        int wi = wih*4 + r;
        float n2 = ov.ep.n2s[0][d][wi] + ov.ep.n2s[1][d][wi]
                 + ov.ep.n2s[2][d][wi] + ov.ep.n2s[3][d][wi];
        fac[r] = (n2 / (1.f + n2)) / sqrtf(n2 + EPSQ);
    }
    // db(D,d,wi) = sum_c u*v : reg-sum over nt + shfl_xor(8) + cross-wave LDS
    float qv[4][4];
    #pragma unroll
    for (int mt = 0; mt < 4; ++mt)
        #pragma unroll
        for (int r = 0; r < 4; ++r) {
            float sum = 0.f;
            #pragma unroll
            for (int nt = 0; nt < 4; ++nt)
                sum += acc[mt][nt][r] * (svv[nt][r] * fac[r]);
            qv[mt][r] = sum;
        }
    #pragma unroll
    for (int mt = 0; mt < 4; ++mt)
        #pragma unroll
        for (int r = 0; r < 4; ++r) qv[mt][r] += __shfl_xor(qv[mt][r], 8);
    if (m16 < 8) {
        #pragma unroll
        for (int mt = 0; mt < 4; ++mt) {
            int D = mt*2 + Dq;
            #pragma unroll
            for (int r = 0; r < 4; ++r) ov.ep.dbs[wv][D][m16][wih*4 + r] = qv[mt][r];
        }
    }
    __syncthreads();
    // b write: 64 (D,d) x 8 wi, float2 runs + per-block Z partial
    {
        int Dd = t >> 2, wip = t & 3;
        int D = Dd >> 3, d2 = Dd & 7;   // D = t>>5, uniform per 32-lane group
        int w = w0 + wip*2;
        float ez = 0.f;
        if (w + 1 < WOUT) {
            int wi = wip*2;
            float2 add;
            add.x = ov.ep.dbs[0][D][d2][wi]   + ov.ep.dbs[1][D][d2][wi]
                  + ov.ep.dbs[2][D][d2][wi]   + ov.ep.dbs[3][D][d2][wi];
            add.y = ov.ep.dbs[0][D][d2][wi+1] + ov.ep.dbs[1][D][d2][wi+1]
                  + ov.ep.dbs[2][D][d2][wi+1] + ov.ep.dbs[3][D][d2][wi+1];
            *(float2*)&bws[((size_t)bb*64 + Dd)*HW + (size_t)h0*WOUT + w] = add;
            ez = expf(add.x) + expf(add.y);   // same values later read as cms
        }
        #pragma unroll
        for (int off = 1; off < 32; off <<= 1) ez += __shfl_xor(ez, off);
        if ((t & 31) == 0)
            Zp[((size_t)bb*8 + D)*BLK_PER_B + h0*12 + wx] = ez;
    }

    // ---- phase 4: Gram G_DD'(d,wi) = sum_c u_cD*u_cD' (VERBATIM r12) ----
    // Each thread holds 4 D's (its Dq half); partner lane^32 has the other 4.
    // r-split dedup: Dq==(r>>1) half accumulates for r. Reduce c over:
    // nt (reg loop), c3=m16>>3 (shfl_xor 8), wv (LDS stage).
    {
        const int c3 = m16 >> 3;
        const int dL = m16 & 7;
        __syncthreads();   // epilogue waves done reading ov.ep before gst reuse
        #pragma unroll
        for (int r = 0; r < 4; ++r) {
            const int rq = r >> 1;          // assigned Dq for this r
            float G36[36];
            #pragma unroll
            for (int j = 0; j < 36; ++j) G36[j] = 0.f;
            #pragma unroll
            for (int nt = 0; nt < 4; ++nt) {
                float u8[8];
                #pragma unroll
                for (int mt = 0; mt < 4; ++mt) {
                    float own = acc[mt][nt][r];
                    float oth = __shfl_xor(own, 32);   // all lanes participate
                    if (Dq == 0) { u8[mt*2]   = own; u8[mt*2+1] = oth; }
                    else         { u8[mt*2+1] = own; u8[mt*2]   = oth; }
                }
                if (Dq == rq) {
                    int idx = 0;
                    #pragma unroll
                    for (int D = 0; D < 8; ++D)
                        #pragma unroll
                        for (int Dp = D; Dp < 8; ++Dp) {
                            G36[idx] += u8[D]*u8[Dp];
                            ++idx;
                        }
                }
            }
            if (Dq == rq) {   // xor-8 partners share Dq; half-wave uniform
                #pragma unroll
                for (int j = 0; j < 36; ++j) G36[j] += __shfl_xor(G36[j], 8);
                if (c3 == 0) {
                    #pragma unroll
                    for (int j = 0; j < 36; ++j) ov.gst[wv][dL*2 + wih][j] = G36[j];
                }
            }
            __syncthreads();
            // cross-wave sum + global write: 16 sites x 36, 144B runs per site
            for (int idx2 = t; idx2 < 16*36; idx2 += 256) {
                int sidx = idx2 / 36, j = idx2 - sidx*36;
                int dd = sidx >> 1, wh = sidx & 1;
                int w = w0 + wh*4 + r;
                if (w < WOUT) {
                    float gv = ov.gst[0][sidx][j] + ov.gst[1][sidx][j]
                             + ov.gst[2][sidx][j] + ov.gst[3][sidx][j];
                    size_t gsite = ((size_t)(bb*DCAP + dd)*HOUT + h0)*WOUT + w;
                    Gm[gsite*36 + j] = gv;
                }
            }
            __syncthreads();   // before next r overwrites gst
        }
    }
}

// ---------------------------------------------------------------------------
// Routing iteration 2 from the Gram matrix (pure streaming; validated r12-r14).
// cm = exp(b1)/Z1, b2 = b1 + fac*(G cm), Z2 partials to Zp.
// ---------------------------------------------------------------------------
template<int ITER>
__global__ __launch_bounds__(256) void gram_route(
    const float* __restrict__ Gm, float* __restrict__ bws,
    const float* __restrict__ Z, float* __restrict__ Zp)
{
    const int k = blockIdx.x, bb = blockIdx.y;
    const int t = threadIdx.x;
    const int local = k*256 + t;
    const bool valid = local < VSITES;
    float ez8[8];
    #pragma unroll
    for (int D = 0; D < 8; ++D) ez8[D] = 0.f;
    if (valid) {
        const int d  = local / HW;
        const int r2 = local - d*HW;
        float bv[8], cm[8];
        if (ITER == 1) {
            const float inv = 1.0f / (float)(DCAP * HW);
            #pragma unroll
            for (int D = 0; D < 8; ++D) { bv[D] = 0.f; cm[D] = inv; }
        } else {
            #pragma unroll
            for (int D = 0; D < 8; ++D) {
                bv[D] = bws[((size_t)(bb*64 + D*8 + d))*HW + r2];
                cm[D] = expf(bv[D]) * (1.0f / Z[bb*8 + D]);
            }
        }
        float g[36];
        const float4* gp = (const float4*)(Gm + (size_t)(bb*VSITES + local)*36);
        #pragma unroll
        for (int q = 0; q < 9; ++q) {
            float4 v = gp[q];
            g[q*4+0] = v.x; g[q*4+1] = v.y; g[q*4+2] = v.z; g[q*4+3] = v.w;
        }
        float tD[8];
        #pragma unroll
        for (int D = 0; D < 8; ++D) tD[D] = 0.f;
        {
            int idx = 0;
            #pragma unroll
            for (int D = 0; D < 8; ++D)
                #pragma unroll
                for (int Dp = D; Dp < 8; ++Dp) {
                    float gv = g[idx]; ++idx;
                    tD[D] += cm[Dp] * gv;
                    if (Dp != D) tD[Dp] += cm[D] * gv;
                }
        }
        float n2 = 0.f;
        #pragma unroll
        for (int D = 0; D < 8; ++D) n2 += cm[D] * tD[D];
        float fac = (n2 / (1.f + n2)) / sqrtf(n2 + EPSQ);
        #pragma unroll
        for (int D = 0; D < 8; ++D) {
            float nb = bv[D] + fac * tD[D];
            bws[((size_t)(bb*64 + D*8 + d))*HW + r2] = nb;
            ez8[D] = expf(nb);
        }
    }
    // block-reduce 8 per-D sums -> contention-free Zp slot
    #pragma unroll
    for (int D = 0; D < 8; ++D)
        #pragma unroll
        for (int off = 1; off < 64; off <<= 1) ez8[D] += __shfl_xor(ez8[D], off);
    __shared__ float ps[4][8];
    if ((t & 63) == 0) {
        #pragma unroll
        for (int D = 0; D < 8; ++D) ps[t >> 6][D] = ez8[D];
    }
    __syncthreads();
    if (t < 8)
        Zp[((size_t)bb*8 + t)*NBLK2 + k] = ps[0][t] + ps[1][t] + ps[2][t] + ps[3][t];
}

// ---------------------------------------------------------------------------
// Pass C: conv + MODE2 epilogue (s output). Verbatim r14 (measured ~150us).
// ---------------------------------------------------------------------------
__global__ __launch_bounds__(256, 2) void conv_s(
    const ushort* __restrict__ xb,
    const ushort* __restrict__ w_hi, const ushort* __restrict__ w_lo,
    const float* __restrict__ bws, const float* __restrict__ Z,
    float* __restrict__ out)
{
    const int t  = threadIdx.x;
    const int wx = blockIdx.x, h0 = blockIdx.y, bb = blockIdx.z;
    const int w0 = wx*8;

    __shared__ __align__(16) ushort a_hi[64][APAD];  // 21504 B
    __shared__ float  cms[64][8];                    // 2048 B
    __shared__ float  invZ[8];
    __shared__ union {                               // 8192 B
        ushort patchb[CIN][DDEP][3][10];             //   phases 0-1 (7680 B)
        float  sout[256][8];                         //   epilogue
    } ov;

    // ---- phase 0: c-coeffs (from b2, Z2) + bf16 patch ----
    if (t < 8) invZ[t] = 1.0f / Z[64 + bb*8 + t];
    for (int v = t; v < 512; v += 256) {
        int Dd = v >> 3, wi = v & 7;
        int w = w0 + wi;
        float bv = (w < WOUT) ? bws[((size_t)bb*64 + Dd)*HW + (size_t)h0*WOUT + w] : 0.f;
        cms[Dd][wi] = expf(bv);
    }
    for (int i = t; i < CIN*DDEP*3*5; i += 256) {
        int ci = i / 120, rem = i - ci*120;
        int D  = rem / 15, r2 = rem - D*15;
        int kh = r2 / 5, uc = r2 - kh*5;
        int xc = w0 + uc*2;
        const ushort* row = xb + (((size_t)(bb*CIN + ci)*DDEP + D)*HIN + (h0+kh))*WIN;
        unsigned v;
        if (xc + 1 < WIN) v = *(const unsigned*)&row[xc];
        else { unsigned e = row[95]; v = e | (e << 16); }
        *(unsigned*)&ov.patchb[ci][D][kh][uc*2] = v;
    }
    __syncthreads();

    // ---- phase 1: im2col ----
    {
        const int site = t >> 2, kg = t & 3;
        const int D = site >> 3, wi = site & 7;
        #pragma unroll
        for (int u2 = 0; u2 < 18; ++u2) {
            int k0 = kg*36 + u2*2;
            int ci0 = k0/9, r0 = k0 - ci0*9, kh0 = r0/3, kw0 = r0 - kh0*3;
            int k1 = k0 + 1;
            int ci1 = k1/9, r1 = k1 - ci1*9, kh1 = r1/3, kw1 = r1 - kh1*3;
            unsigned lo = ov.patchb[ci0][D][kh0][wi+kw0];
            unsigned hi = ov.patchb[ci1][D][kh1][wi+kw1];
            *(unsigned*)&a_hi[site][k0] = lo | (hi << 16);
        }
        if (t < 64) {
            #pragma unroll
            for (int kk = KTOT; kk < KTILES*32; kk += 2)
                *(unsigned*)&a_hi[t][kk] = 0u;
        }
    }
    __syncthreads();

    // ---- phase 2: MFMA K-loop ----
    const int wv = t >> 6, lane = t & 63;
    const int m16 = lane & 15, quad = lane >> 4;
    f32x4 acc[4][4];
    #pragma unroll
    for (int mt = 0; mt < 4; ++mt)
        #pragma unroll
        for (int nt = 0; nt < 4; ++nt)
            acc[mt][nt] = (f32x4){0.f, 0.f, 0.f, 0.f};

    #pragma unroll
    for (int kt = 0; kt < KTILES; ++kt) {
        bf16x8 ah[4];
        #pragma unroll
        for (int mt = 0; mt < 4; ++mt)
            ah[mt] = *(const bf16x8*)&a_hi[mt*16 + m16][kt*32 + quad*8];
        #pragma unroll
        for (int nt = 0; nt < 4; ++nt) {
            size_t off = (((size_t)kt*16 + (wv*4 + nt))*64 + lane)*8;
            bf16x8 bh = *(const bf16x8*)&w_hi[off];
            bf16x8 bl = *(const bf16x8*)&w_lo[off];
            #pragma unroll
            for (int mt = 0; mt < 4; ++mt) {
                acc[mt][nt] = __builtin_amdgcn_mfma_f32_16x16x32_bf16(ah[mt], bh, acc[mt][nt], 0, 0, 0);
                acc[mt][nt] = __builtin_amdgcn_mfma_f32_16x16x32_bf16(ah[mt], bl, acc[mt][nt], 0, 0, 0);
            }
        }
    }

    // ---- phase 3: s epilogue (verbatim r7-verified MODE2 path) ----
    const int d   = m16 & 7;
    const int Dq  = quad >> 1;
    const int wih = quad & 1;
    float svv[4][4];
    {
        float cmw[4][4];
        #pragma unroll
        for (int mt = 0; mt < 4; ++mt) {
            int D = mt*2 + Dq;
            float iz = invZ[D];
            #pragma unroll
            for (int r = 0; r < 4; ++r) cmw[mt][r] = cms[D*8 + d][wih*4 + r] * iz;
        }
        #pragma unroll
        for (int nt = 0; nt < 4; ++nt)
            #pragma unroll
            for (int r = 0; r < 4; ++r) {
                float partial = 0.f;
                #pragma unroll
                for (int mt = 0; mt < 4; ++mt) partial += cmw[mt][r]*acc[mt][nt][r];
                partial += __shfl_xor(partial, 32);
                svv[nt][r] = partial;   // uniform in lane bit5
            }
    }
    if (quad < 2) {   // one Dq copy per (wih, m16, nt)
        #pragma unroll
        for (int nt = 0; nt < 4; ++nt) {
            int ch = wv*64 + nt*16 + m16;
            #pragma unroll
            for (int r = 0; r < 4; ++r) ov.sout[ch][wih*4 + r] = svv[nt][r];
        }
    }
    __syncthreads();
    for (int i = t; i < 1024; i += 256) {
        int c2 = i >> 2, wip = i & 3;
        int w = w0 + wip*2;
        if (w + 1 < WOUT) {
            float2 v2 = { ov.sout[c2][wip*2], ov.sout[c2][wip*2 + 1] };
            *(float2*)&out[((size_t)bb*CH + c2)*HW + (size_t)h0*WOUT + w] = v2;
        }
    }
}

// ---------------------------------------------------------------------------
// Workspace (~119 MB total; ws >= 213 MB proven in r11 — single path):
//   bws 18.1 | Z 512B | Zp 288KB | wfrags 320KB | xb 18.9 | Gm 81.4
// ---------------------------------------------------------------------------
extern "C" void kernel_launch(void* const* d_in, const int* in_sizes, int n_in,
                              void* d_out, int out_size, void* d_ws, size_t ws_size,
                              hipStream_t stream)
{
    (void)in_sizes; (void)n_in; (void)out_size; (void)ws_size;
    const float* x     = (const float*)d_in[0];
    const float* wconv = (const float*)d_in[1];
    float* out = (float*)d_out;

    float*  bws  = (float*)d_ws;
    float*  Z    = bws + B_ELEMS;            // Z1 = Z[0..63], Z2 = Z[64..127]
    float*  Zp   = Z + 128;                  // 64*BLK_PER_B partials (both uses)
    ushort* w_hi = (ushort*)(Zp + 64*BLK_PER_B);
    ushort* w_lo = w_hi + WFRAG_ELEMS;
    ushort* xb   = w_lo + WFRAG_ELEMS;       // bf16 x cache
    size_t  base = (size_t)((char*)(xb + XN) - (char*)d_ws);
    size_t  goff = (base + 255) & ~(size_t)255;
    float*  Gm   = (float*)((char*)d_ws + goff);

    const dim3 grid(12, 94, 8);
    build_wfrag<<<dim3(16, KTILES), 64, 0, stream>>>(wconv, w_hi, w_lo);
    xconvert<<<(unsigned)(XN/4/256), 256, 0, stream>>>(x, xb);
    conv_ag<<<grid, 256, 0, stream>>>(xb, w_hi, w_lo, bws, Zp, Gm);
    zreduce<<<64, 256, 0, stream>>>(Zp, Z, 0, BLK_PER_B);
    gram_route<2><<<dim3(NBLK2, 8), 256, 0, stream>>>(Gm, bws, Z, Zp);
    zreduce<<<64, 256, 0, stream>>>(Zp, Z, 64, NBLK2);
    conv_s<<<grid, 256, 0, stream>>>(xb, w_hi, w_lo, bws, Z, out);
}

// Round 9
// 561.388 us; speedup vs baseline: 2.4958x; 1.0266x over previous
//
#include <hip/hip_runtime.h>
#include <math.h>

#define CIN   16
#define DDEP  8      // conv depth (routing "D")
#define HIN   96
#define WIN   96
#define HOUT  94
#define WOUT  94
#define HW    (HOUT*WOUT)        // 8836
#define CH    256                 // out channels = c*8+d
#define DCAP  8
#define KTOT  (CIN*9)             // 144
#define KTILES 5                  // K padded to 160
#define APAD  168                 // A row stride (bf16 elems)
#define EPSQ  1e-8f

#define B_ELEMS ((size_t)8*DDEP*DCAP*HW)          // 4,524,032 floats
#define WFRAG_ELEMS ((size_t)KTILES*16*64*8)      // 40,960 per half
#define VSITES (DCAP*HW)                          // 70,688 sites per batch
#define NBLK2  277                                // ceil(70688/256)
#define XN ((size_t)8*CIN*DDEP*HIN*WIN)           // 9,437,184 x elems
#define G_BYTES ((size_t)8*VSITES*36*4)           // 81,432,576 B

typedef __attribute__((ext_vector_type(8))) short bf16x8;
typedef __attribute__((ext_vector_type(4))) float f32x4;

// explicit RNE float->bf16 bit conversion
__device__ __forceinline__ ushort f2bf(float f) {
    unsigned u = __float_as_uint(f);
    return (ushort)((u + 0x7FFFu + ((u >> 16) & 1u)) >> 16);
}
__device__ __forceinline__ float bf2f(ushort h) {
    return __uint_as_float(((unsigned)h) << 16);
}

// ---------------------------------------------------------------------------
// W -> MFMA B-fragment order, hi/lo split. frag[kt][nt][lane][j] = W[k][n],
// k = kt*32 + (lane>>4)*8 + j (0 for k>=144), n = nt*16 + (lane&15).
// ---------------------------------------------------------------------------
__global__ __launch_bounds__(64) void build_wfrag(
    const float* __restrict__ w, ushort* __restrict__ w_hi, ushort* __restrict__ w_lo)
{
    const int lane = threadIdx.x;
    const int nt = blockIdx.x, kt = blockIdx.y;
    const int n  = nt*16 + (lane & 15);
    const int kb = kt*32 + (lane >> 4)*8;
    size_t off = (((size_t)kt*16 + nt)*64 + lane)*8;
    for (int j = 0; j < 8; ++j) {
        int k = kb + j;
        float v = (k < KTOT) ? w[(size_t)n*KTOT + k] : 0.f;
        ushort hi = f2bf(v);
        float  r  = v - bf2f(hi);
        ushort lo = f2bf(r);
        w_hi[off + j] = hi; w_lo[off + j] = lo;
    }
}

// ---------------------------------------------------------------------------
// One-shot x -> bf16 side-cache (18.9 MB). Conv passes stage ushort patches
// from this (identical bits to in-pass f2bf -> bitwise-same A tiles).
// ---------------------------------------------------------------------------
__global__ __launch_bounds__(256) void xconvert(
    const float* __restrict__ x, ushort* __restrict__ xb)
{
    size_t i = (size_t)blockIdx.x*256 + threadIdx.x;
    if (i*4 >= XN) return;
    float4 v = ((const float4*)x)[i];
    ushort4 o;
    o.x = f2bf(v.x); o.y = f2bf(v.y); o.z = f2bf(v.z); o.w = f2bf(v.w);
    ((ushort4*)xb)[i] = o;
}

// ---------------------------------------------------------------------------
// Z reduce from contention-free per-block partials (r10 lesson: NEVER funnel
// per-block Z through same-address device atomics — serialized ~+120us/pass).
// ---------------------------------------------------------------------------
__global__ __launch_bounds__(256) void zreduce(
    const float* __restrict__ Zp, float* __restrict__ Z, int dst, int count)
{
    const int bd = blockIdx.x;
    const float* p = Zp + (size_t)bd * count;
    float s = 0.f;
    for (int i = threadIdx.x; i < count; i += 256) s += p[i];
    #pragma unroll
    for (int off = 1; off < 64; off <<= 1) s += __shfl_xor(s, off);
    __shared__ float ps[4];
    if ((threadIdx.x & 63) == 0) ps[threadIdx.x >> 6] = s;
    __syncthreads();
    if (threadIdx.x == 0) Z[dst + bd] = ps[0] + ps[1] + ps[2] + ps[3];
}

// ---------------------------------------------------------------------------
// Pass A (r18): conv + Gram write ONLY. The iter1 (MODE0) epilogue is gone —
// b1 is computed by gram_route<1> from G (validated end-to-end in r13/r14).
// Block: (wx,h0,bb) -> 8 D x 1 h-row x 8 w; M=64, N=256.
// acc[mt][nt][r]: m = mt*16 + quad*4 + r -> D = mt*2 + (quad>>1),
//                 wi = (quad&1)*4 + r;  ch = wv*64 + nt*16 + m16.
// GW phase: VERBATIM r12 form (per-r barrier loop, Dq==rq half-lane guard) —
// r17 measured no-spill (conv_ag 301us, WRITE 113MB = exactly b+G+Zp).
// r13/r14 lesson: the all-lane 2-r-batched GW rewrite spilled ~130 regs/thread
// (1.2GB writes, 3x slower); the per-r barriers/guards bound liveness.
// DO NOT restructure GW. Keep __launch_bounds__(256,2).
// Spill tripwire: WRITE_SIZE must be ~82 MB (G only).
// ---------------------------------------------------------------------------
__global__ __launch_bounds__(256, 2) void conv_g(
    const ushort* __restrict__ xb,
    const ushort* __restrict__ w_hi, const ushort* __restrict__ w_lo,
    float* __restrict__ Gm)
{
    const int t  = threadIdx.x;
    const int wx = blockIdx.x, h0 = blockIdx.y, bb = blockIdx.z;
    const int w0 = wx*8;

    __shared__ __align__(16) ushort a_hi[64][APAD];  // 21504 B (all phases)
    __shared__ union {                               // 9216 B, lifetime-disjoint
        ushort patchb[CIN][DDEP][3][10];             //   phases 0-1 (7680 B)
        float gst[4][16][36];                        //   Gram staging (post-MFMA)
    } ov;

    // ---- phase 0: stage bf16 x patch (uint pair loads, clamped tail) ----
    for (int i = t; i < CIN*DDEP*3*5; i += 256) {
        int ci = i / 120, rem = i - ci*120;
        int D  = rem / 15, r2 = rem - D*15;
        int kh = r2 / 5, uc = r2 - kh*5;
        int xc = w0 + uc*2;
        const ushort* row = xb + (((size_t)(bb*CIN + ci)*DDEP + D)*HIN + (h0+kh))*WIN;
        unsigned v;
        if (xc + 1 < WIN) v = *(const unsigned*)&row[xc];
        else { unsigned e = row[95]; v = e | (e << 16); }  // clamp: garbage cols feed only invalid sites
        *(unsigned*)&ov.patchb[ci][D][kh][uc*2] = v;
    }
    __syncthreads();

    // ---- phase 1: im2col (pure ushort packing; no f2bf) ----
    {
        const int site = t >> 2, kg = t & 3;     // site = D*8 + wi
        const int D = site >> 3, wi = site & 7;
        #pragma unroll
        for (int u2 = 0; u2 < 18; ++u2) {
            int k0 = kg*36 + u2*2;
            int ci0 = k0/9, r0 = k0 - ci0*9, kh0 = r0/3, kw0 = r0 - kh0*3;
            int k1 = k0 + 1;
            int ci1 = k1/9, r1 = k1 - ci1*9, kh1 = r1/3, kw1 = r1 - kh1*3;
            unsigned lo = ov.patchb[ci0][D][kh0][wi+kw0];
            unsigned hi = ov.patchb[ci1][D][kh1][wi+kw1];
            *(unsigned*)&a_hi[site][k0] = lo | (hi << 16);
        }
        if (t < 64) {
            #pragma unroll
            for (int kk = KTOT; kk < KTILES*32; kk += 2)
                *(unsigned*)&a_hi[t][kk] = 0u;
        }
    }
    __syncthreads();

    // ---- phase 2: MFMA K-loop ----
    const int wv = t >> 6, lane = t & 63;
    const int m16 = lane & 15, quad = lane >> 4;
    const int Dq  = quad >> 1;      // D parity bit (lane bit5)
    const int wih = quad & 1;       // wi half (lane bit4)
    f32x4 acc[4][4];
    #pragma unroll
    for (int mt = 0; mt < 4; ++mt)
        #pragma unroll
        for (int nt = 0; nt < 4; ++nt)
            acc[mt][nt] = (f32x4){0.f, 0.f, 0.f, 0.f};

    #pragma unroll
    for (int kt = 0; kt < KTILES; ++kt) {
        bf16x8 ah[4];
        #pragma unroll
        for (int mt = 0; mt < 4; ++mt)
            ah[mt] = *(const bf16x8*)&a_hi[mt*16 + m16][kt*32 + quad*8];
        #pragma unroll
        for (int nt = 0; nt < 4; ++nt) {
            size_t off = (((size_t)kt*16 + (wv*4 + nt))*64 + lane)*8;
            bf16x8 bh = *(const bf16x8*)&w_hi[off];
            bf16x8 bl = *(const bf16x8*)&w_lo[off];
            #pragma unroll
            for (int mt = 0; mt < 4; ++mt) {
                acc[mt][nt] = __builtin_amdgcn_mfma_f32_16x16x32_bf16(ah[mt], bh, acc[mt][nt], 0, 0, 0);
                acc[mt][nt] = __builtin_amdgcn_mfma_f32_16x16x32_bf16(ah[mt], bl, acc[mt][nt], 0, 0, 0);
            }
        }
    }

    // ---- phase 3: Gram G_DD'(d,wi) = sum_c u_cD*u_cD' (VERBATIM r12) ----
    // Each thread holds 4 D's (its Dq half); partner lane^32 has the other 4.
    // r-split dedup: Dq==(r>>1) half accumulates for r. Reduce c over:
    // nt (reg loop), c3=m16>>3 (shfl_xor 8), wv (LDS stage).
    {
        const int c3 = m16 >> 3;
        const int dL = m16 & 7;
        __syncthreads();   // all waves past phase-1 reads before gst reuse
        #pragma unroll
        for (int r = 0; r < 4; ++r) {
            const int rq = r >> 1;          // assigned Dq for this r
            float G36[36];
            #pragma unroll
            for (int j = 0; j < 36; ++j) G36[j] = 0.f;
            #pragma unroll
            for (int nt = 0; nt < 4; ++nt) {
                float u8[8];
                #pragma unroll
                for (int mt = 0; mt < 4; ++mt) {
                    float own = acc[mt][nt][r];
                    float oth = __shfl_xor(own, 32);   // all lanes participate
                    if (Dq == 0) { u8[mt*2]   = own; u8[mt*2+1] = oth; }
                    else         { u8[mt*2+1] = own; u8[mt*2]   = oth; }
                }
                if (Dq == rq) {
                    int idx = 0;
                    #pragma unroll
                    for (int D = 0; D < 8; ++D)
                        #pragma unroll
                        for (int Dp = D; Dp < 8; ++Dp) {
                            G36[idx] += u8[D]*u8[Dp];
                            ++idx;
                        }
                }
            }
            if (Dq == rq) {   // xor-8 partners share Dq; half-wave uniform
                #pragma unroll
                for (int j = 0; j < 36; ++j) G36[j] += __shfl_xor(G36[j], 8);
                if (c3 == 0) {
                    #pragma unroll
                    for (int j = 0; j < 36; ++j) ov.gst[wv][dL*2 + wih][j] = G36[j];
                }
            }
            __syncthreads();
            // cross-wave sum + global write: 16 sites x 36, 144B runs per site
            for (int idx2 = t; idx2 < 16*36; idx2 += 256) {
                int sidx = idx2 / 36, j = idx2 - sidx*36;
                int dd = sidx >> 1, wh = sidx & 1;
                int w = w0 + wh*4 + r;
                if (w < WOUT) {
                    float gv = ov.gst[0][sidx][j] + ov.gst[1][sidx][j]
                             + ov.gst[2][sidx][j] + ov.gst[3][sidx][j];
                    size_t gsite = ((size_t)(bb*DCAP + dd)*HOUT + h0)*WOUT + w;
                    Gm[gsite*36 + j] = gv;
                }
            }
            __syncthreads();   // before next r overwrites gst
        }
    }
}

// ---------------------------------------------------------------------------
// Routing iterations 1 AND 2 from the Gram matrix (both pure streaming).
// ITER 1: cm uniform (b0=0), b1 = fac*(G cm), Z1 partials (validated r13/r14).
// ITER 2: cm = exp(b1)/Z1, b2 = b1 + fac*(G cm), Z2 partials (validated r12+).
// ---------------------------------------------------------------------------
template<int ITER>
__global__ __launch_bounds__(256) void gram_route(
    const float* __restrict__ Gm, float* __restrict__ bws,
    const float* __restrict__ Z, float* __restrict__ Zp)
{
    const int k = blockIdx.x, bb = blockIdx.y;
    const int t = threadIdx.x;
    const int local = k*256 + t;
    const bool valid = local < VSITES;
    float ez8[8];
    #pragma unroll
    for (int D = 0; D < 8; ++D) ez8[D] = 0.f;
    if (valid) {
        const int d  = local / HW;
        const int r2 = local - d*HW;
        float bv[8], cm[8];
        if (ITER == 1) {
            const float inv = 1.0f / (float)(DCAP * HW);
            #pragma unroll
            for (int D = 0; D < 8; ++D) { bv[D] = 0.f; cm[D] = inv; }
        } else {
            #pragma unroll
            for (int D = 0; D < 8; ++D) {
                bv[D] = bws[((size_t)(bb*64 + D*8 + d))*HW + r2];
                cm[D] = expf(bv[D]) * (1.0f / Z[bb*8 + D]);
            }
        }
        float g[36];
        const float4* gp = (const float4*)(Gm + (size_t)(bb*VSITES + local)*36);
        #pragma unroll
        for (int q = 0; q < 9; ++q) {
            float4 v = gp[q];
            g[q*4+0] = v.x; g[q*4+1] = v.y; g[q*4+2] = v.z; g[q*4+3] = v.w;
        }
        float tD[8];
        #pragma unroll
        for (int D = 0; D < 8; ++D) tD[D] = 0.f;
        {
            int idx = 0;
            #pragma unroll
            for (int D = 0; D < 8; ++D)
                #pragma unroll
                for (int Dp = D; Dp < 8; ++Dp) {
                    float gv = g[idx]; ++idx;
                    tD[D] += cm[Dp] * gv;
                    if (Dp != D) tD[Dp] += cm[D] * gv;
                }
        }
        float n2 = 0.f;
        #pragma unroll
        for (int D = 0; D < 8; ++D) n2 += cm[D] * tD[D];
        float fac = (n2 / (1.f + n2)) / sqrtf(n2 + EPSQ);
        #pragma unroll
        for (int D = 0; D < 8; ++D) {
            float nb = bv[D] + fac * tD[D];
            bws[((size_t)(bb*64 + D*8 + d))*HW + r2] = nb;
            ez8[D] = expf(nb);
        }
    }
    // block-reduce 8 per-D sums -> contention-free Zp slot
    #pragma unroll
    for (int D = 0; D < 8; ++D)
        #pragma unroll
        for (int off = 1; off < 64; off <<= 1) ez8[D] += __shfl_xor(ez8[D], off);
    __shared__ float ps[4][8];
    if ((t & 63) == 0) {
        #pragma unroll
        for (int D = 0; D < 8; ++D) ps[t >> 6][D] = ez8[D];
    }
    __syncthreads();
    if (t < 8)
        Zp[((size_t)bb*8 + t)*NBLK2 + k] = ps[0][t] + ps[1][t] + ps[2][t] + ps[3][t];
}

// ---------------------------------------------------------------------------
// Pass C: conv + MODE2 epilogue (s output). Verbatim r17 (measured ~150us).
// ---------------------------------------------------------------------------
__global__ __launch_bounds__(256, 2) void conv_s(
    const ushort* __restrict__ xb,
    const ushort* __restrict__ w_hi, const ushort* __restrict__ w_lo,
    const float* __restrict__ bws, const float* __restrict__ Z,
    float* __restrict__ out)
{
    const int t  = threadIdx.x;
    const int wx = blockIdx.x, h0 = blockIdx.y, bb = blockIdx.z;
    const int w0 = wx*8;

    __shared__ __align__(16) ushort a_hi[64][APAD];  // 21504 B
    __shared__ float  cms[64][8];                    // 2048 B
    __shared__ float  invZ[8];
    __shared__ union {                               // 8192 B
        ushort patchb[CIN][DDEP][3][10];             //   phases 0-1 (7680 B)
        float  sout[256][8];                         //   epilogue
    } ov;

    // ---- phase 0: c-coeffs (from b2, Z2) + bf16 patch ----
    if (t < 8) invZ[t] = 1.0f / Z[64 + bb*8 + t];
    for (int v = t; v < 512; v += 256) {
        int Dd = v >> 3, wi = v & 7;
        int w = w0 + wi;
        float bv = (w < WOUT) ? bws[((size_t)bb*64 + Dd)*HW + (size_t)h0*WOUT + w] : 0.f;
        cms[Dd][wi] = expf(bv);
    }
    for (int i = t; i < CIN*DDEP*3*5; i += 256) {
        int ci = i / 120, rem = i - ci*120;
        int D  = rem / 15, r2 = rem - D*15;
        int kh = r2 / 5, uc = r2 - kh*5;
        int xc = w0 + uc*2;
        const ushort* row = xb + (((size_t)(bb*CIN + ci)*DDEP + D)*HIN + (h0+kh))*WIN;
        unsigned v;
        if (xc + 1 < WIN) v = *(const unsigned*)&row[xc];
        else { unsigned e = row[95]; v = e | (e << 16); }
        *(unsigned*)&ov.patchb[ci][D][kh][uc*2] = v;
    }
    __syncthreads();

    // ---- phase 1: im2col ----
    {
        const int site = t >> 2, kg = t & 3;
        const int D = site >> 3, wi = site & 7;
        #pragma unroll
        for (int u2 = 0; u2 < 18; ++u2) {
            int k0 = kg*36 + u2*2;
            int ci0 = k0/9, r0 = k0 - ci0*9, kh0 = r0/3, kw0 = r0 - kh0*3;
            int k1 = k0 + 1;
            int ci1 = k1/9, r1 = k1 - ci1*9, kh1 = r1/3, kw1 = r1 - kh1*3;
            unsigned lo = ov.patchb[ci0][D][kh0][wi+kw0];
            unsigned hi = ov.patchb[ci1][D][kh1][wi+kw1];
            *(unsigned*)&a_hi[site][k0] = lo | (hi << 16);
        }
        if (t < 64) {
            #pragma unroll
            for (int kk = KTOT; kk < KTILES*32; kk += 2)
                *(unsigned*)&a_hi[t][kk] = 0u;
        }
    }
    __syncthreads();

    // ---- phase 2: MFMA K-loop ----
    const int wv = t >> 6, lane = t & 63;
    const int m16 = lane & 15, quad = lane >> 4;
    f32x4 acc[4][4];
    #pragma unroll
    for (int mt = 0; mt < 4; ++mt)
        #pragma unroll
        for (int nt = 0; nt < 4; ++nt)
            acc[mt][nt] = (f32x4){0.f, 0.f, 0.f, 0.f};

    #pragma unroll
    for (int kt = 0; kt < KTILES; ++kt) {
        bf16x8 ah[4];
        #pragma unroll
        for (int mt = 0; mt < 4; ++mt)
            ah[mt] = *(const bf16x8*)&a_hi[mt*16 + m16][kt*32 + quad*8];
        #pragma unroll
        for (int nt = 0; nt < 4; ++nt) {
            size_t off = (((size_t)kt*16 + (wv*4 + nt))*64 + lane)*8;
            bf16x8 bh = *(const bf16x8*)&w_hi[off];
            bf16x8 bl = *(const bf16x8*)&w_lo[off];
            #pragma unroll
            for (int mt = 0; mt < 4; ++mt) {
                acc[mt][nt] = __builtin_amdgcn_mfma_f32_16x16x32_bf16(ah[mt], bh, acc[mt][nt], 0, 0, 0);
                acc[mt][nt] = __builtin_amdgcn_mfma_f32_16x16x32_bf16(ah[mt], bl, acc[mt][nt], 0, 0, 0);
            }
        }
    }

    // ---- phase 3: s epilogue (verbatim r7-verified MODE2 path) ----
    const int d   = m16 & 7;
    const int Dq  = quad >> 1;
    const int wih = quad & 1;
    float svv[4][4];
    {
        float cmw[4][4];
        #pragma unroll
        for (int mt = 0; mt < 4; ++mt) {
            int D = mt*2 + Dq;
            float iz = invZ[D];
            #pragma unroll
            for (int r = 0; r < 4; ++r) cmw[mt][r] = cms[D*8 + d][wih*4 + r] * iz;
        }
        #pragma unroll
        for (int nt = 0; nt < 4; ++nt)
            #pragma unroll
            for (int r = 0; r < 4; ++r) {
                float partial = 0.f;
                #pragma unroll
                for (int mt = 0; mt < 4; ++mt) partial += cmw[mt][r]*acc[mt][nt][r];
                partial += __shfl_xor(partial, 32);
                svv[nt][r] = partial;   // uniform in lane bit5
            }
    }
    if (quad < 2) {   // one Dq copy per (wih, m16, nt)
        #pragma unroll
        for (int nt = 0; nt < 4; ++nt) {
            int ch = wv*64 + nt*16 + m16;
            #pragma unroll
            for (int r = 0; r < 4; ++r) ov.sout[ch][wih*4 + r] = svv[nt][r];
        }
    }
    __syncthreads();
    for (int i = t; i < 1024; i += 256) {
        int c2 = i >> 2, wip = i & 3;
        int w = w0 + wip*2;
        if (w + 1 < WOUT) {
            float2 v2 = { ov.sout[c2][wip*2], ov.sout[c2][wip*2 + 1] };
            *(float2*)&out[((size_t)bb*CH + c2)*HW + (size_t)h0*WOUT + w] = v2;
        }
    }
}

// ---------------------------------------------------------------------------
// Workspace (~119 MB total; ws >= 213 MB proven in r11 — single path):
//   bws 18.1 | Z 512B | Zp 70KB | wfrags 320KB | xb 18.9 | Gm 81.4
// ---------------------------------------------------------------------------
extern "C" void kernel_launch(void* const* d_in, const int* in_sizes, int n_in,
                              void* d_out, int out_size, void* d_ws, size_t ws_size,
                              hipStream_t stream)
{
    (void)in_sizes; (void)n_in; (void)out_size; (void)ws_size;
    const float* x     = (const float*)d_in[0];
    const float* wconv = (const float*)d_in[1];
    float* out = (float*)d_out;

    float*  bws  = (float*)d_ws;
    float*  Z    = bws + B_ELEMS;            // Z1 = Z[0..63], Z2 = Z[64..127]
    float*  Zp   = Z + 128;                  // 64*NBLK2 partials
    ushort* w_hi = (ushort*)(Zp + 64*NBLK2);
    ushort* w_lo = w_hi + WFRAG_ELEMS;
    ushort* xb   = w_lo + WFRAG_ELEMS;       // bf16 x cache
    size_t  base = (size_t)((char*)(xb + XN) - (char*)d_ws);
    size_t  goff = (base + 255) & ~(size_t)255;
    float*  Gm   = (float*)((char*)d_ws + goff);

    const dim3 grid(12, 94, 8);
    build_wfrag<<<dim3(16, KTILES), 64, 0, stream>>>(wconv, w_hi, w_lo);
    xconvert<<<(unsigned)(XN/4/256), 256, 0, stream>>>(x, xb);
    conv_g<<<grid, 256, 0, stream>>>(xb, w_hi, w_lo, Gm);
    gram_route<1><<<dim3(NBLK2, 8), 256, 0, stream>>>(Gm, bws, Z, Zp);
    zreduce<<<64, 256, 0, stream>>>(Zp, Z, 0, NBLK2);
    gram_route<2><<<dim3(NBLK2, 8), 256, 0, stream>>>(Gm, bws, Z, Zp);
    zreduce<<<64, 256, 0, stream>>>(Zp, Z, 64, NBLK2);
    conv_s<<<grid, 256, 0, stream>>>(xb, w_hi, w_lo, bws, Z, out);
}